// Round 3
// baseline (5701.444 us; speedup 1.0000x reference)
//
#include <hip/hip_runtime.h>
#include <stdint.h>
#include <math.h>

#define SEQ 256
#define BATCH 1024
#define IN_DIM 512
#define HID 256
#define NCOL 1024   // 4 gates * HID

typedef float f32x4 __attribute__((ext_vector_type(4)));
typedef short bf16x8 __attribute__((ext_vector_type(8)));
typedef unsigned short u16;

__device__ __forceinline__ u16 f2b(float f) {
  union { float f; uint32_t u; } v; v.f = f;
  uint32_t r = v.u + 0x7FFFu + ((v.u >> 16) & 1u);
  return (u16)(r >> 16);
}

// Precise (OCML) transcendentals kept this round — isolate the dtype fix.
__device__ __forceinline__ float sigmoid_p(float x) {
  return 1.0f / (1.0f + expf(-x));
}

// ---------------------------------------------------------------------------
// prep: convert/swizzle weights to bf16 fragment-major layouts.
// Wxb: [ntile(64)][kg(64)][n%16(16)][e(8)]  (x part, k in [0,512))
// Whb: [ntile(64)][kg(32)][n%16(16)][e(8)]  (h part, k in [512,768))
// n = gate*256 + n', gates ordered f,i,u,o.
// ---------------------------------------------------------------------------
__global__ __launch_bounds__(256) void qlstm_prep(
    const float* __restrict__ Wf, const float* __restrict__ Wi,
    const float* __restrict__ Wu, const float* __restrict__ Wo,
    u16* __restrict__ Wxb, u16* __restrict__ Whb) {
  int idx = blockIdx.x * 256 + threadIdx.x;
  if (idx >= NCOL * 768) return;
  int n = idx / 768, k = idx - n * 768;
  int g = n >> 8, nn = n & 255;
  const float* W = (g == 0) ? Wf : (g == 1) ? Wi : (g == 2) ? Wu : Wo;
  u16 b = f2b(W[nn * 768 + k]);
  int nt = n >> 4, n16 = n & 15;
  if (k < IN_DIM) {
    int kg = k >> 3, e = k & 7;
    Wxb[(((size_t)nt * 64 + kg) * 16 + n16) * 8 + e] = b;
  } else {
    int kh = k - IN_DIM, kg = kh >> 3, e = kh & 7;
    Whb[(((size_t)nt * 32 + kg) * 16 + n16) * 8 + e] = b;
  }
}

// ---------------------------------------------------------------------------
// K1: Zx[m][n] = X[m][:512] @ Wx.T   (f32 out), m = t_local*1024 + b
// 128x128 tile, BK=32, 4 waves (2x2), A staged fp32->bf16 via LDS, B direct.
// ---------------------------------------------------------------------------
__global__ __launch_bounds__(256) void qlstm_k1(
    const float* __restrict__ Xc, const u16* __restrict__ Wxb,
    float* __restrict__ Zx) {
  __shared__ u16 A_lds[4][128][8];   // [kg][row][e], 8KB
  __shared__ float ZS[128][128];     // 64KB epilogue staging (f32)
  int bid = blockIdx.x;
  int mt = bid >> 3, ntb = bid & 7;
  int m0 = mt * 128, n0 = ntb * 128;
  int tid = threadIdx.x, lane = tid & 63, wave = tid >> 6;
  int wm = wave >> 1, wn = wave & 1;

  f32x4 acc[4][4];
#pragma unroll
  for (int a = 0; a < 4; ++a)
#pragma unroll
    for (int b = 0; b < 4; ++b) acc[a][b] = (f32x4){0.f, 0.f, 0.f, 0.f};

  for (int kb = 0; kb < IN_DIM; kb += 32) {
#pragma unroll
    for (int i = 0; i < 4; ++i) {
      int slot = i * 256 + tid;
      int row = slot >> 3, kseg = slot & 7;
      float4 xv = *(const float4*)(Xc + (size_t)(m0 + row) * IN_DIM + kb + kseg * 4);
      uint2 pk;
      pk.x = (uint32_t)f2b(xv.x) | ((uint32_t)f2b(xv.y) << 16);
      pk.y = (uint32_t)f2b(xv.z) | ((uint32_t)f2b(xv.w) << 16);
      *(uint2*)&A_lds[kseg >> 1][row][(kseg & 1) * 4] = pk;
    }
    __syncthreads();
    bf16x8 af[4];
#pragma unroll
    for (int fm = 0; fm < 4; ++fm) {
      int row = wm * 64 + fm * 16 + (lane & 15);
      af[fm] = *(const bf16x8*)&A_lds[lane >> 4][row][0];
    }
    int kgb = (kb >> 3) + (lane >> 4);
#pragma unroll
    for (int fn = 0; fn < 4; ++fn) {
      int ntile = ntb * 8 + wn * 4 + fn;
      bf16x8 bfr = *(const bf16x8*)(Wxb + (((size_t)ntile * 64 + kgb) * 16 + (lane & 15)) * 8);
#pragma unroll
      for (int fm = 0; fm < 4; ++fm)
        acc[fm][fn] = __builtin_amdgcn_mfma_f32_16x16x32_bf16(af[fm], bfr, acc[fm][fn], 0, 0, 0);
    }
    __syncthreads();
  }
  // epilogue: stage to LDS (transpose from frag layout), then coalesced store
#pragma unroll
  for (int fm = 0; fm < 4; ++fm) {
#pragma unroll
    for (int fn = 0; fn < 4; ++fn) {
      int col = wn * 64 + fn * 16 + (lane & 15);
      int rb = wm * 64 + fm * 16 + (lane >> 4) * 4;
#pragma unroll
      for (int r = 0; r < 4; ++r) ZS[rb + r][col] = acc[fm][fn][r];
    }
  }
  __syncthreads();
#pragma unroll
  for (int i = 0; i < 16; ++i) {
    int slot = i * 256 + tid;
    int row = slot >> 5, c4 = (slot & 31) * 4;
    *(float4*)(Zx + (size_t)(m0 + row) * NCOL + n0 + c4) = *(const float4*)&ZS[row][c4];
  }
}

// ---------------------------------------------------------------------------
// K2: recurrent kernel. 64 WGs x 512 threads (8 waves). WG owns 16 batch rows
// for all timesteps: z = Zx + h@Wh.T + (bias+p); qlayer cumprod scan; gates;
// c,f update; h -> LDS (bf16, MFMA feed) + f32 out.
// ---------------------------------------------------------------------------
__global__ __launch_bounds__(512) void qlstm_k2(
    const float* __restrict__ Zx, const u16* __restrict__ Whb,
    const float* __restrict__ bf_, const float* __restrict__ bi_,
    const float* __restrict__ bu_, const float* __restrict__ bo_,
    const float* __restrict__ pf_, const float* __restrict__ pi_,
    const float* __restrict__ pu_, const float* __restrict__ po_,
    u16* __restrict__ h_state, float* __restrict__ c_state,
    float* __restrict__ outp, int t0, int Tc) {
  __shared__ float z_lds[16][1028];      // padded
  __shared__ float zx_lds[16][1024];
  __shared__ u16 h_lds[16][32][8];       // [row][kg ^ (row&7)][e]
  __shared__ float bp_lds[1024];

  int tid = threadIdx.x, lane = tid & 63, wave = tid >> 6;
  int r0 = blockIdx.x * 16;

  for (int i = tid; i < NCOL; i += 512) {
    int g = i >> 8, nn = i & 255;
    float bb = (g == 0 ? bf_ : g == 1 ? bi_ : g == 2 ? bu_ : bo_)[nn];
    float pp = (g == 0 ? pf_ : g == 1 ? pi_ : g == 2 ? pu_ : po_)[nn];
    bp_lds[i] = bb + pp;
  }
  int urow = tid >> 5, ucb = tid & 31, ucol = ucb * 8;
  uint4 hq = *(const uint4*)(h_state + (size_t)(r0 + urow) * HID + ucol);
  *(uint4*)&h_lds[urow][ucb ^ (urow & 7)][0] = hq;
  float c[8], hcur[8];
  {
    float4 c0 = *(const float4*)(c_state + (size_t)(r0 + urow) * HID + ucol);
    float4 c1 = *(const float4*)(c_state + (size_t)(r0 + urow) * HID + ucol + 4);
    c[0] = c0.x; c[1] = c0.y; c[2] = c0.z; c[3] = c0.w;
    c[4] = c1.x; c[5] = c1.y; c[6] = c1.z; c[7] = c1.w;
#pragma unroll
    for (int j = 0; j < 8; ++j) hcur[j] = 0.f;   // h0 = 0 (exact h kept in f32)
  }
  __syncthreads();

  int arow = lane & 15, agrp = lane >> 4;
  for (int tt = 0; tt < Tc; ++tt) {
    // (1) issue Zx tile loads early (consumed after MFMA)
    float4 zxr[8];
#pragma unroll
    for (int j = 0; j < 8; ++j) {
      int off = j * 512 + tid;
      int zrow = off >> 8, zcol = (off & 255) * 4;
      zxr[j] = *(const float4*)(Zx + ((size_t)tt * BATCH + r0 + zrow) * NCOL + zcol);
    }
    // (2) MFMA: z_h = h @ Wh.T ; wave owns 128 cols (8 ntiles)
    bf16x8 afr[8];
#pragma unroll
    for (int kt = 0; kt < 8; ++kt) {
      int kg = kt * 4 + agrp;
      afr[kt] = *(const bf16x8*)&h_lds[arow][kg ^ (arow & 7)][0];
    }
    f32x4 acc[8];
#pragma unroll
    for (int nt = 0; nt < 8; ++nt) {
      acc[nt] = (f32x4){0.f, 0.f, 0.f, 0.f};
      int ntile = wave * 8 + nt;
#pragma unroll
      for (int kt = 0; kt < 8; ++kt) {
        int kg = kt * 4 + agrp;
        bf16x8 bfr = *(const bf16x8*)(Whb + (((size_t)ntile * 32 + kg) * 16 + arow) * 8);
        acc[nt] = __builtin_amdgcn_mfma_f32_16x16x32_bf16(afr[kt], bfr, acc[nt], 0, 0, 0);
      }
    }
    // (3) land Zx tile in LDS
#pragma unroll
    for (int j = 0; j < 8; ++j) {
      int off = j * 512 + tid;
      int zrow = off >> 8, zcol = (off & 255) * 4;
      *(float4*)&zx_lds[zrow][zcol] = zxr[j];
    }
    __syncthreads();
    // (4) cos(z + bias + p) -> z_lds
#pragma unroll
    for (int nt = 0; nt < 8; ++nt) {
      int col = (wave * 8 + nt) * 16 + arow;
      float bp = bp_lds[col];
#pragma unroll
      for (int r = 0; r < 4; ++r) {
        int row = agrp * 4 + r;
        float arg = acc[nt][r] + bp + zx_lds[row][col];
        z_lds[row][col] = cosf(arg);
      }
    }
    __syncthreads();
    // (6) cumprod scan: 64 scans of 256, one per (row,gate); wave does 8
#pragma unroll
    for (int j = 0; j < 8; ++j) {
      int s = wave * 8 + j, srow = s & 15, sg = s >> 4;
      float4 v = *(const float4*)&z_lds[srow][sg * 256 + lane * 4];
      float p = v.x * v.y * v.z * v.w;
#pragma unroll
      for (int d = 1; d < 64; d <<= 1) {
        float tproc = __shfl_up(p, (unsigned)d);
        p *= (lane >= d) ? tproc : 1.0f;
      }
      float ex = __shfl_up(p, 1u);
      ex = (lane == 0) ? 1.0f : ex;
      float4 ov;
      ov.x = ex * v.x; ov.y = ov.x * v.y; ov.z = ov.y * v.z; ov.w = ov.z * v.w;
      *(float4*)&z_lds[srow][sg * 256 + lane * 4] = ov;
    }
    __syncthreads();
    // (8) gates, state update, h out (f32)
    float q[4][8];
#pragma unroll
    for (int g = 0; g < 4; ++g) {
      float4 qa = *(const float4*)&z_lds[urow][g * 256 + ucol];
      float4 qb = *(const float4*)&z_lds[urow][g * 256 + ucol + 4];
      q[g][0] = qa.x; q[g][1] = qa.y; q[g][2] = qa.z; q[g][3] = qa.w;
      q[g][4] = qb.x; q[g][5] = qb.y; q[g][6] = qb.z; q[g][7] = qb.w;
    }
    u16 hb16[8];
#pragma unroll
    for (int j2 = 0; j2 < 8; ++j2) {
      float fg = sigmoid_p(q[0][j2]);
      float ig = sigmoid_p(q[1][j2]);
      float ug = tanhf(q[2][j2]);
      float og = sigmoid_p(q[3][j2]);
      c[j2] = fg * c[j2] + ig * ug;
      float hv = og * tanhf(c[j2]);
      hcur[j2] = hv;
      hb16[j2] = f2b(hv);
    }
    uint4 hv4;
    hv4.x = (uint32_t)hb16[0] | ((uint32_t)hb16[1] << 16);
    hv4.y = (uint32_t)hb16[2] | ((uint32_t)hb16[3] << 16);
    hv4.z = (uint32_t)hb16[4] | ((uint32_t)hb16[5] << 16);
    hv4.w = (uint32_t)hb16[6] | ((uint32_t)hb16[7] << 16);
    hq = hv4;
    *(uint4*)&h_lds[urow][ucb ^ (urow & 7)][0] = hv4;   // bf16 copy for MFMA
    int t = t0 + tt;
    {
      float4 h0, h1;
      h0.x = hcur[0]; h0.y = hcur[1]; h0.z = hcur[2]; h0.w = hcur[3];
      h1.x = hcur[4]; h1.y = hcur[5]; h1.z = hcur[6]; h1.w = hcur[7];
      float* op = outp + ((size_t)t * BATCH + r0 + urow) * HID + ucol;
      *(float4*)op = h0;
      *(float4*)(op + 4) = h1;
    }
    __syncthreads();
  }
  // persist state across chunks
  *(uint4*)(h_state + (size_t)(r0 + urow) * HID + ucol) = hq;
  {
    float4 c0, c1;
    c0.x = c[0]; c0.y = c[1]; c0.z = c[2]; c0.w = c[3];
    c1.x = c[4]; c1.y = c[5]; c1.z = c[6]; c1.w = c[7];
    *(float4*)(c_state + (size_t)(r0 + urow) * HID + ucol) = c0;
    *(float4*)(c_state + (size_t)(r0 + urow) * HID + ucol + 4) = c1;
  }
  if (t0 + Tc == SEQ) {
    // hx then cx, f32, concatenated after outs
    size_t base = (size_t)SEQ * BATCH * HID;
    float* hp = outp + base + (size_t)(r0 + urow) * HID + ucol;
    float4 h0, h1;
    h0.x = hcur[0]; h0.y = hcur[1]; h0.z = hcur[2]; h0.w = hcur[3];
    h1.x = hcur[4]; h1.y = hcur[5]; h1.z = hcur[6]; h1.w = hcur[7];
    *(float4*)hp = h0;
    *(float4*)(hp + 4) = h1;
    float* cp = outp + base + (size_t)BATCH * HID + (size_t)(r0 + urow) * HID + ucol;
    float4 c0, c1;
    c0.x = c[0]; c0.y = c[1]; c0.z = c[2]; c0.w = c[3];
    c1.x = c[4]; c1.y = c[5]; c1.z = c[6]; c1.w = c[7];
    *(float4*)cp = c0;
    *(float4*)(cp + 4) = c1;
  }
}

// ---------------------------------------------------------------------------
extern "C" void kernel_launch(void* const* d_in, const int* in_sizes, int n_in,
                              void* d_out, int out_size, void* d_ws, size_t ws_size,
                              hipStream_t stream) {
  const float* X  = (const float*)d_in[0];
  const float* Wf = (const float*)d_in[1];
  const float* bf_ = (const float*)d_in[2];
  const float* Wi = (const float*)d_in[3];
  const float* bi_ = (const float*)d_in[4];
  const float* Wu = (const float*)d_in[5];
  const float* bu_ = (const float*)d_in[6];
  const float* Wo = (const float*)d_in[7];
  const float* bo_ = (const float*)d_in[8];
  const float* pf_ = (const float*)d_in[9];
  const float* pi_ = (const float*)d_in[10];
  const float* pu_ = (const float*)d_in[11];
  const float* po_ = (const float*)d_in[12];

  char* ws = (char*)d_ws;
  u16* Whb = (u16*)ws;                                 // 512 KB
  u16* Wxb = (u16*)(ws + (512 << 10));                 // 1 MB
  u16* h_state = (u16*)(ws + (1536 << 10));            // 512 KB
  float* c_state = (float*)(ws + (2048 << 10));        // 1 MB
  float* Zx = (float*)(ws + (3072 << 10));             // Tc * 4 MB (f32)

  size_t fixed = (size_t)3072 << 10;
  int Tc = 256;
  while (Tc > 1 && fixed + (size_t)Tc * (4u << 20) > ws_size) Tc >>= 1;
  if (fixed + (size_t)Tc * (4u << 20) > ws_size) return;  // ws too small

  qlstm_prep<<<3072, 256, 0, stream>>>(Wf, Wi, Wu, Wo, Wxb, Whb);
  hipMemsetAsync(h_state, 0, (512 << 10) + (1 << 20), stream);  // h_state + c_state

  for (int t0 = 0; t0 < SEQ; t0 += Tc) {
    qlstm_k1<<<dim3(Tc * 64), 256, 0, stream>>>(X + (size_t)t0 * BATCH * IN_DIM, Wxb, Zx);
    qlstm_k2<<<dim3(64), 512, 0, stream>>>(Zx, Whb, bf_, bi_, bu_, bo_,
                                           pf_, pi_, pu_, po_,
                                           h_state, c_state, (float*)d_out, t0, Tc);
  }
}

// Round 4
// 4425.727 us; speedup vs baseline: 1.2883x; 1.2883x over previous
//
#include <hip/hip_runtime.h>
#include <stdint.h>
#include <math.h>

#define SEQ 256
#define BATCH 1024
#define IN_DIM 512
#define HID 256
#define NCOL 1024   // 4 gates * HID

typedef float f32x4 __attribute__((ext_vector_type(4)));
typedef short bf16x8 __attribute__((ext_vector_type(8)));
typedef unsigned short u16;

__device__ __forceinline__ u16 f2b(float f) {
  union { float f; uint32_t u; } v; v.f = f;
  uint32_t r = v.u + 0x7FFFu + ((v.u >> 16) & 1u);
  return (u16)(r >> 16);
}

// Fast transcendentals: v_cos (revolutions), v_exp (2^x), v_rcp.
// Abs errors ~1e-5 — negligible vs the 0.0078 bf16-weight error floor.
#define LOG2E 1.4426950408889634f
__device__ __forceinline__ float fcos(float x) {
  return __builtin_amdgcn_cosf(x * 0.15915494309189535f);  // cos(2*pi*s)
}
__device__ __forceinline__ float fsig(float x) {
  return __builtin_amdgcn_rcpf(1.0f + __builtin_amdgcn_exp2f(-x * LOG2E));
}
__device__ __forceinline__ float ftanh(float x) {
  float e = __builtin_amdgcn_exp2f(x * (2.0f * LOG2E));
  return (e - 1.0f) * __builtin_amdgcn_rcpf(e + 1.0f);
}

// ---------------------------------------------------------------------------
// prep: convert/swizzle weights to bf16 fragment-major layouts.
// Wxb: [ntile(64)][kg(64)][n%16(16)][e(8)]  (x part, k in [0,512))
// Whb: [ntile(64)][kg(32)][n%16(16)][e(8)]  (h part, k in [512,768))
// ---------------------------------------------------------------------------
__global__ __launch_bounds__(256) void qlstm_prep(
    const float* __restrict__ Wf, const float* __restrict__ Wi,
    const float* __restrict__ Wu, const float* __restrict__ Wo,
    u16* __restrict__ Wxb, u16* __restrict__ Whb) {
  int idx = blockIdx.x * 256 + threadIdx.x;
  if (idx >= NCOL * 768) return;
  int n = idx / 768, k = idx - n * 768;
  int g = n >> 8, nn = n & 255;
  const float* W = (g == 0) ? Wf : (g == 1) ? Wi : (g == 2) ? Wu : Wo;
  u16 b = f2b(W[nn * 768 + k]);
  int nt = n >> 4, n16 = n & 15;
  if (k < IN_DIM) {
    int kg = k >> 3, e = k & 7;
    Wxb[(((size_t)nt * 64 + kg) * 16 + n16) * 8 + e] = b;
  } else {
    int kh = k - IN_DIM, kg = kh >> 3, e = kh & 7;
    Whb[(((size_t)nt * 32 + kg) * 16 + n16) * 8 + e] = b;
  }
}

// ---------------------------------------------------------------------------
// K1: Zx[m][n] = X[m][:512] @ Wx.T  (f32 out) — unchanged this round.
// ---------------------------------------------------------------------------
__global__ __launch_bounds__(256) void qlstm_k1(
    const float* __restrict__ Xc, const u16* __restrict__ Wxb,
    float* __restrict__ Zx) {
  __shared__ u16 A_lds[4][128][8];
  __shared__ float ZS[128][128];
  int bid = blockIdx.x;
  int mt = bid >> 3, ntb = bid & 7;
  int m0 = mt * 128, n0 = ntb * 128;
  int tid = threadIdx.x, lane = tid & 63, wave = tid >> 6;
  int wm = wave >> 1, wn = wave & 1;

  f32x4 acc[4][4];
#pragma unroll
  for (int a = 0; a < 4; ++a)
#pragma unroll
    for (int b = 0; b < 4; ++b) acc[a][b] = (f32x4){0.f, 0.f, 0.f, 0.f};

  for (int kb = 0; kb < IN_DIM; kb += 32) {
#pragma unroll
    for (int i = 0; i < 4; ++i) {
      int slot = i * 256 + tid;
      int row = slot >> 3, kseg = slot & 7;
      float4 xv = *(const float4*)(Xc + (size_t)(m0 + row) * IN_DIM + kb + kseg * 4);
      uint2 pk;
      pk.x = (uint32_t)f2b(xv.x) | ((uint32_t)f2b(xv.y) << 16);
      pk.y = (uint32_t)f2b(xv.z) | ((uint32_t)f2b(xv.w) << 16);
      *(uint2*)&A_lds[kseg >> 1][row][(kseg & 1) * 4] = pk;
    }
    __syncthreads();
    bf16x8 af[4];
#pragma unroll
    for (int fm = 0; fm < 4; ++fm) {
      int row = wm * 64 + fm * 16 + (lane & 15);
      af[fm] = *(const bf16x8*)&A_lds[lane >> 4][row][0];
    }
    int kgb = (kb >> 3) + (lane >> 4);
#pragma unroll
    for (int fn = 0; fn < 4; ++fn) {
      int ntile = ntb * 8 + wn * 4 + fn;
      bf16x8 bfr = *(const bf16x8*)(Wxb + (((size_t)ntile * 64 + kgb) * 16 + (lane & 15)) * 8);
#pragma unroll
      for (int fm = 0; fm < 4; ++fm)
        acc[fm][fn] = __builtin_amdgcn_mfma_f32_16x16x32_bf16(af[fm], bfr, acc[fm][fn], 0, 0, 0);
    }
    __syncthreads();
  }
#pragma unroll
  for (int fm = 0; fm < 4; ++fm) {
#pragma unroll
    for (int fn = 0; fn < 4; ++fn) {
      int col = wn * 64 + fn * 16 + (lane & 15);
      int rb = wm * 64 + fm * 16 + (lane >> 4) * 4;
#pragma unroll
      for (int r = 0; r < 4; ++r) ZS[rb + r][col] = acc[fm][fn][r];
    }
  }
  __syncthreads();
#pragma unroll
  for (int i = 0; i < 16; ++i) {
    int slot = i * 256 + tid;
    int row = slot >> 5, c4 = (slot & 31) * 4;
    *(float4*)(Zx + (size_t)(m0 + row) * NCOL + n0 + c4) = *(const float4*)&ZS[row][c4];
  }
}

// ---------------------------------------------------------------------------
// K2 v2: 64 WGs x 1024 threads (16 waves, 4/SIMD). WG owns 16 batch rows.
// Fast transcendentals. Phases: MFMA(h@Wh.T) | cos | scan | gates.
// ---------------------------------------------------------------------------
__global__ __launch_bounds__(1024) void qlstm_k2(
    const float* __restrict__ Zx, const u16* __restrict__ Whb,
    const float* __restrict__ bf_, const float* __restrict__ bi_,
    const float* __restrict__ bu_, const float* __restrict__ bo_,
    const float* __restrict__ pf_, const float* __restrict__ pi_,
    const float* __restrict__ pu_, const float* __restrict__ po_,
    u16* __restrict__ h_state, float* __restrict__ c_state,
    float* __restrict__ outp, int t0, int Tc) {
  __shared__ float z_lds[16][1028];      // padded
  __shared__ float zx_lds[16][1024];
  __shared__ u16 h_lds[16][32][8];       // [row][kg ^ (row&7)][e]
  __shared__ float bp_lds[1024];

  int tid = threadIdx.x, lane = tid & 63, wave = tid >> 6;  // wave 0..15
  int r0 = blockIdx.x * 16;

  {
    int g = tid >> 8, nn = tid & 255;
    float bb = (g == 0 ? bf_ : g == 1 ? bi_ : g == 2 ? bu_ : bo_)[nn];
    float pp = (g == 0 ? pf_ : g == 1 ? pi_ : g == 2 ? pu_ : po_)[nn];
    bp_lds[tid] = bb + pp;
  }
  // per-thread state ownership: row grow (16), 4 cols at gcol
  int grow = tid >> 6, gcol = (tid & 63) * 4;
  int ucb = (tid & 63) >> 1, uhalf = (tid & 63) & 1;   // uint2 slot in h_lds
  uint2 hq = *(const uint2*)(h_state + (size_t)(r0 + grow) * HID + gcol);
  *(uint2*)&h_lds[grow][ucb ^ (grow & 7)][uhalf * 4] = hq;
  float c[4], hcur[4];
  {
    float4 cv = *(const float4*)(c_state + (size_t)(r0 + grow) * HID + gcol);
    c[0] = cv.x; c[1] = cv.y; c[2] = cv.z; c[3] = cv.w;
#pragma unroll
    for (int j = 0; j < 4; ++j) hcur[j] = 0.f;
  }
  __syncthreads();

  int arow = lane & 15, agrp = lane >> 4;
  for (int tt = 0; tt < Tc; ++tt) {
    // (1) issue Zx tile loads early (consumed after MFMA)
    float4 zxr[4];
#pragma unroll
    for (int j = 0; j < 4; ++j) {
      int off = j * 1024 + tid;
      int zrow = off >> 8, zcol = (off & 255) * 4;
      zxr[j] = *(const float4*)(Zx + ((size_t)tt * BATCH + r0 + zrow) * NCOL + zcol);
    }
    // (2) MFMA: z_h = h @ Wh.T ; wave owns 64 cols (4 ntiles)
    bf16x8 afr[8];
#pragma unroll
    for (int kt = 0; kt < 8; ++kt) {
      int kg = kt * 4 + agrp;
      afr[kt] = *(const bf16x8*)&h_lds[arow][kg ^ (arow & 7)][0];
    }
    f32x4 acc[4];
#pragma unroll
    for (int nt = 0; nt < 4; ++nt) {
      acc[nt] = (f32x4){0.f, 0.f, 0.f, 0.f};
      int ntile = wave * 4 + nt;
#pragma unroll
      for (int kt = 0; kt < 8; ++kt) {
        int kg = kt * 4 + agrp;
        bf16x8 bfr = *(const bf16x8*)(Whb + (((size_t)ntile * 32 + kg) * 16 + arow) * 8);
        acc[nt] = __builtin_amdgcn_mfma_f32_16x16x32_bf16(afr[kt], bfr, acc[nt], 0, 0, 0);
      }
    }
    // (3) land Zx tile in LDS
#pragma unroll
    for (int j = 0; j < 4; ++j) {
      int off = j * 1024 + tid;
      int zrow = off >> 8, zcol = (off & 255) * 4;
      *(float4*)&zx_lds[zrow][zcol] = zxr[j];
    }
    __syncthreads();
    // (4) cos(z + bias + p) -> z_lds
#pragma unroll
    for (int nt = 0; nt < 4; ++nt) {
      int col = (wave * 4 + nt) * 16 + arow;
      float bp = bp_lds[col];
#pragma unroll
      for (int r = 0; r < 4; ++r) {
        int row = agrp * 4 + r;
        float arg = acc[nt][r] + bp + zx_lds[row][col];
        z_lds[row][col] = fcos(arg);
      }
    }
    __syncthreads();
    // (6) cumprod scan: 64 scans of 256 (16 rows x 4 gates); wave does 4
#pragma unroll
    for (int j = 0; j < 4; ++j) {
      int s = wave * 4 + j, srow = s & 15, sg = s >> 4;
      float4 v = *(const float4*)&z_lds[srow][sg * 256 + lane * 4];
      float p = v.x * v.y * v.z * v.w;
#pragma unroll
      for (int d = 1; d < 64; d <<= 1) {
        float tproc = __shfl_up(p, (unsigned)d);
        p *= (lane >= d) ? tproc : 1.0f;
      }
      float ex = __shfl_up(p, 1u);
      ex = (lane == 0) ? 1.0f : ex;
      float4 ov;
      ov.x = ex * v.x; ov.y = ov.x * v.y; ov.z = ov.y * v.z; ov.w = ov.z * v.w;
      *(float4*)&z_lds[srow][sg * 256 + lane * 4] = ov;
    }
    __syncthreads();
    // (8) gates, state update, h out (f32); 4 elems per thread
    float q[4][4];
#pragma unroll
    for (int g = 0; g < 4; ++g) {
      float4 qa = *(const float4*)&z_lds[grow][g * 256 + gcol];
      q[g][0] = qa.x; q[g][1] = qa.y; q[g][2] = qa.z; q[g][3] = qa.w;
    }
    u16 hb16[4];
#pragma unroll
    for (int j2 = 0; j2 < 4; ++j2) {
      float fg = fsig(q[0][j2]);
      float ig = fsig(q[1][j2]);
      float ug = ftanh(q[2][j2]);
      float og = fsig(q[3][j2]);
      c[j2] = fg * c[j2] + ig * ug;
      float hv = og * ftanh(c[j2]);
      hcur[j2] = hv;
      hb16[j2] = f2b(hv);
    }
    uint2 hv2;
    hv2.x = (uint32_t)hb16[0] | ((uint32_t)hb16[1] << 16);
    hv2.y = (uint32_t)hb16[2] | ((uint32_t)hb16[3] << 16);
    hq = hv2;
    *(uint2*)&h_lds[grow][ucb ^ (grow & 7)][uhalf * 4] = hv2;  // bf16 for MFMA
    int t = t0 + tt;
    {
      float4 h0;
      h0.x = hcur[0]; h0.y = hcur[1]; h0.z = hcur[2]; h0.w = hcur[3];
      *(float4*)(outp + ((size_t)t * BATCH + r0 + grow) * HID + gcol) = h0;
    }
    __syncthreads();
  }
  // persist state across chunks
  *(uint2*)(h_state + (size_t)(r0 + grow) * HID + gcol) = hq;
  {
    float4 cv;
    cv.x = c[0]; cv.y = c[1]; cv.z = c[2]; cv.w = c[3];
    *(float4*)(c_state + (size_t)(r0 + grow) * HID + gcol) = cv;
  }
  if (t0 + Tc == SEQ) {
    // hx then cx, f32, concatenated after outs
    size_t base = (size_t)SEQ * BATCH * HID;
    float4 h0;
    h0.x = hcur[0]; h0.y = hcur[1]; h0.z = hcur[2]; h0.w = hcur[3];
    *(float4*)(outp + base + (size_t)(r0 + grow) * HID + gcol) = h0;
    float4 cv;
    cv.x = c[0]; cv.y = c[1]; cv.z = c[2]; cv.w = c[3];
    *(float4*)(outp + base + (size_t)BATCH * HID + (size_t)(r0 + grow) * HID + gcol) = cv;
  }
}

// ---------------------------------------------------------------------------
extern "C" void kernel_launch(void* const* d_in, const int* in_sizes, int n_in,
                              void* d_out, int out_size, void* d_ws, size_t ws_size,
                              hipStream_t stream) {
  const float* X  = (const float*)d_in[0];
  const float* Wf = (const float*)d_in[1];
  const float* bf_ = (const float*)d_in[2];
  const float* Wi = (const float*)d_in[3];
  const float* bi_ = (const float*)d_in[4];
  const float* Wu = (const float*)d_in[5];
  const float* bu_ = (const float*)d_in[6];
  const float* Wo = (const float*)d_in[7];
  const float* bo_ = (const float*)d_in[8];
  const float* pf_ = (const float*)d_in[9];
  const float* pi_ = (const float*)d_in[10];
  const float* pu_ = (const float*)d_in[11];
  const float* po_ = (const float*)d_in[12];

  char* ws = (char*)d_ws;
  u16* Whb = (u16*)ws;                                 // 512 KB
  u16* Wxb = (u16*)(ws + (512 << 10));                 // 1 MB
  u16* h_state = (u16*)(ws + (1536 << 10));            // 512 KB
  float* c_state = (float*)(ws + (2048 << 10));        // 1 MB
  float* Zx = (float*)(ws + (3072 << 10));             // Tc * 4 MB (f32)

  size_t fixed = (size_t)3072 << 10;
  int Tc = 256;
  while (Tc > 1 && fixed + (size_t)Tc * (4u << 20) > ws_size) Tc >>= 1;
  if (fixed + (size_t)Tc * (4u << 20) > ws_size) return;

  qlstm_prep<<<3072, 256, 0, stream>>>(Wf, Wi, Wu, Wo, Wxb, Whb);
  hipMemsetAsync(h_state, 0, (512 << 10) + (1 << 20), stream);

  for (int t0 = 0; t0 < SEQ; t0 += Tc) {
    qlstm_k1<<<dim3(Tc * 64), 256, 0, stream>>>(X + (size_t)t0 * BATCH * IN_DIM, Wxb, Zx);
    qlstm_k2<<<dim3(64), 1024, 0, stream>>>(Zx, Whb, bf_, bi_, bu_, bo_,
                                            pf_, pi_, pu_, po_,
                                            h_state, c_state, (float*)d_out, t0, Tc);
  }
}

// Round 5
// 3654.255 us; speedup vs baseline: 1.5602x; 1.2111x over previous
//
#include <hip/hip_runtime.h>
#include <stdint.h>
#include <math.h>

#define SEQ 256
#define BATCH 1024
#define IN_DIM 512
#define HID 256
#define NCOL 1024   // 4 gates * HID

typedef float f32x4 __attribute__((ext_vector_type(4)));
typedef short bf16x8 __attribute__((ext_vector_type(8)));
typedef unsigned short u16;

__device__ __forceinline__ u16 f2b(float f) {
  union { float f; uint32_t u; } v; v.f = f;
  uint32_t r = v.u + 0x7FFFu + ((v.u >> 16) & 1u);
  return (u16)(r >> 16);
}
__device__ __forceinline__ float b2f(uint32_t h16) {
  union { uint32_t u; float f; } v; v.u = h16 << 16;
  return v.f;
}

#define LOG2E 1.4426950408889634f
__device__ __forceinline__ float fcos(float x) {
  return __builtin_amdgcn_cosf(x * 0.15915494309189535f);  // v_cos takes revolutions
}
__device__ __forceinline__ float fsig(float x) {
  return __builtin_amdgcn_rcpf(1.0f + __builtin_amdgcn_exp2f(-x * LOG2E));
}
__device__ __forceinline__ float ftanh(float x) {
  float e = __builtin_amdgcn_exp2f(x * (2.0f * LOG2E));
  return (e - 1.0f) * __builtin_amdgcn_rcpf(e + 1.0f);
}

// ---------------------------------------------------------------------------
// prep: weights -> bf16 fragment-major. Wxb: [nt(64)][kg(64)][n16][e8];
// Whb: [nt(64)][kg(32)][n16][e8]. n = gate*256 + n' (f,i,u,o).
// ---------------------------------------------------------------------------
__global__ __launch_bounds__(256) void qlstm_prep(
    const float* __restrict__ Wf, const float* __restrict__ Wi,
    const float* __restrict__ Wu, const float* __restrict__ Wo,
    u16* __restrict__ Wxb, u16* __restrict__ Whb) {
  int idx = blockIdx.x * 256 + threadIdx.x;
  if (idx >= NCOL * 768) return;
  int n = idx / 768, k = idx - n * 768;
  int g = n >> 8, nn = n & 255;
  const float* W = (g == 0) ? Wf : (g == 1) ? Wi : (g == 2) ? Wu : Wo;
  u16 b = f2b(W[nn * 768 + k]);
  int nt = n >> 4, n16 = n & 15;
  if (k < IN_DIM) {
    int kg = k >> 3, e = k & 7;
    Wxb[(((size_t)nt * 64 + kg) * 16 + n16) * 8 + e] = b;
  } else {
    int kh = k - IN_DIM, kg = kh >> 3, e = kh & 7;
    Whb[(((size_t)nt * 32 + kg) * 16 + n16) * 8 + e] = b;
  }
}

// ---------------------------------------------------------------------------
// K1: Zxf = X @ Wx.T in bf16 FRAGMENT-MAJOR: [rowblk][ntile][lane][r(4)],
// rowblk = m/16 (m = t_local*1024 + b), ntile = n/16. Direct acc-layout
// store — no epilogue LDS staging.
// ---------------------------------------------------------------------------
__global__ __launch_bounds__(256) void qlstm_k1(
    const float* __restrict__ Xc, const u16* __restrict__ Wxb,
    u16* __restrict__ Zxf) {
  __shared__ u16 A_lds[4][128][8];   // [kg][row][e], 8KB
  int bid = blockIdx.x;
  int mt = bid >> 3, ntb = bid & 7;
  int m0 = mt * 128;
  int tid = threadIdx.x, lane = tid & 63, wave = tid >> 6;
  int wm = wave >> 1, wn = wave & 1;

  f32x4 acc[4][4];
#pragma unroll
  for (int a = 0; a < 4; ++a)
#pragma unroll
    for (int b = 0; b < 4; ++b) acc[a][b] = (f32x4){0.f, 0.f, 0.f, 0.f};

  for (int kb = 0; kb < IN_DIM; kb += 32) {
#pragma unroll
    for (int i = 0; i < 4; ++i) {
      int slot = i * 256 + tid;
      int row = slot >> 3, kseg = slot & 7;
      float4 xv = *(const float4*)(Xc + (size_t)(m0 + row) * IN_DIM + kb + kseg * 4);
      uint2 pk;
      pk.x = (uint32_t)f2b(xv.x) | ((uint32_t)f2b(xv.y) << 16);
      pk.y = (uint32_t)f2b(xv.z) | ((uint32_t)f2b(xv.w) << 16);
      *(uint2*)&A_lds[kseg >> 1][row][(kseg & 1) * 4] = pk;
    }
    __syncthreads();
    bf16x8 af[4];
#pragma unroll
    for (int fm = 0; fm < 4; ++fm) {
      int row = wm * 64 + fm * 16 + (lane & 15);
      af[fm] = *(const bf16x8*)&A_lds[lane >> 4][row][0];
    }
    int kgb = (kb >> 3) + (lane >> 4);
#pragma unroll
    for (int fn = 0; fn < 4; ++fn) {
      int ntile = ntb * 8 + wn * 4 + fn;
      bf16x8 bfr = *(const bf16x8*)(Wxb + (((size_t)ntile * 64 + kgb) * 16 + (lane & 15)) * 8);
#pragma unroll
      for (int fm = 0; fm < 4; ++fm)
        acc[fm][fn] = __builtin_amdgcn_mfma_f32_16x16x32_bf16(af[fm], bfr, acc[fm][fn], 0, 0, 0);
    }
    __syncthreads();
  }
  // fragment-major bf16 store: uint2 per lane per fragment, 512B/instr
#pragma unroll
  for (int fm = 0; fm < 4; ++fm) {
#pragma unroll
    for (int fn = 0; fn < 4; ++fn) {
      int rowblk = mt * 8 + wm * 4 + fm;
      int ntile = ntb * 8 + wn * 4 + fn;
      uint2 pk;
      pk.x = (uint32_t)f2b(acc[fm][fn][0]) | ((uint32_t)f2b(acc[fm][fn][1]) << 16);
      pk.y = (uint32_t)f2b(acc[fm][fn][2]) | ((uint32_t)f2b(acc[fm][fn][3]) << 16);
      *(uint2*)(Zxf + (((size_t)rowblk * 64 + ntile) * 64 + lane) * 4) = pk;
    }
  }
}

// ---------------------------------------------------------------------------
// K2 v3: 64 WGs x 1024 thr. 2 barriers/step. Wave w owns: MFMA ntiles
// [4w,4w+4) AND scan/gates for batch row w. Zx prefetched to regs (frag
// layout); cos fused after MFMA in-reg; scan+gates fused in-reg.
// ---------------------------------------------------------------------------
__global__ __launch_bounds__(1024) void qlstm_k2(
    const u16* __restrict__ Zxf, const u16* __restrict__ Whb,
    const float* __restrict__ bf_, const float* __restrict__ bi_,
    const float* __restrict__ bu_, const float* __restrict__ bo_,
    const float* __restrict__ pf_, const float* __restrict__ pi_,
    const float* __restrict__ pu_, const float* __restrict__ po_,
    u16* __restrict__ h_state, float* __restrict__ c_state,
    float* __restrict__ outp, int t0, int Tc) {
  __shared__ float z_lds[16][1026];   // stride 1026: 4*1026 % 32 == 8 -> conflict-free scatter
  __shared__ u16 h_lds[16][32][8];    // [row][kg ^ (row&7)][e]
  __shared__ float bp_lds[1024];

  int tid = threadIdx.x, lane = tid & 63, w = tid >> 6;  // w: wave 0..15 == batch row
  int rg = blockIdx.x;                 // row-group 0..63
  int r0 = rg * 16;

  {
    int g = tid >> 8, nn = tid & 255;
    float bb = (g == 0 ? bf_ : g == 1 ? bi_ : g == 2 ? bu_ : bo_)[nn];
    float pp = (g == 0 ? pf_ : g == 1 ? pi_ : g == 2 ? pu_ : po_)[nn];
    bp_lds[tid] = bb + pp;
  }
  int gcol = lane * 4;                 // this thread's 4 hidden cols (row w)
  uint2 hq = *(const uint2*)(h_state + (size_t)(r0 + w) * HID + gcol);
  *(uint2*)&h_lds[w][(lane >> 1) ^ (w & 7)][(lane & 1) * 4] = hq;
  float c[4];
  {
    float4 cv = *(const float4*)(c_state + (size_t)(r0 + w) * HID + gcol);
    c[0] = cv.x; c[1] = cv.y; c[2] = cv.z; c[3] = cv.w;
  }
  float hprev[4] = {0.f, 0.f, 0.f, 0.f};
  __syncthreads();

  int arow = lane & 15, agrp = lane >> 4;
  // Zx fragment base for (tt, ntile=w*4+nt): elements (((tt*64+rg)*64 + w*4+nt)*64 + lane)*4
  const u16* zbase = Zxf + (((size_t)rg * 64 + (size_t)w * 4) * 64 + lane) * 4;
  const size_t ZT = (size_t)64 * 64 * 64 * 4;   // elements per timestep
  uint2 zc[4], zn[4];
#pragma unroll
  for (int nt = 0; nt < 4; ++nt)
    zc[nt] = *(const uint2*)(zbase + (size_t)nt * 256);

  for (int tt = 0; tt < Tc; ++tt) {
    // (A) prefetch Zx for tt+1
    size_t tnext = (size_t)((tt + 1 < Tc) ? tt + 1 : tt) * ZT;
#pragma unroll
    for (int nt = 0; nt < 4; ++nt)
      zn[nt] = *(const uint2*)(zbase + tnext + (size_t)nt * 256);
    // (B) store h(tt-1): drains under MFMA phase, not at a barrier
    if (tt > 0) {
      float4 h4; h4.x = hprev[0]; h4.y = hprev[1]; h4.z = hprev[2]; h4.w = hprev[3];
      *(float4*)(outp + ((size_t)(t0 + tt - 1) * BATCH + r0 + w) * HID + gcol) = h4;
    }
    // (C) A-fragments of h
    bf16x8 afr[8];
#pragma unroll
    for (int kt = 0; kt < 8; ++kt)
      afr[kt] = *(const bf16x8*)&h_lds[arow][(kt * 4 + agrp) ^ (arow & 7)][0];
    // (D) MFMA: wave w computes cols [64w, 64w+64)
    f32x4 acc[4];
#pragma unroll
    for (int nt = 0; nt < 4; ++nt) {
      acc[nt] = (f32x4){0.f, 0.f, 0.f, 0.f};
      int ntile = w * 4 + nt;
#pragma unroll
      for (int kt = 0; kt < 8; ++kt) {
        int kg = kt * 4 + agrp;
        bf16x8 bfr = *(const bf16x8*)(Whb + (((size_t)ntile * 32 + kg) * 16 + arow) * 8);
        acc[nt] = __builtin_amdgcn_mfma_f32_16x16x32_bf16(afr[kt], bfr, acc[nt], 0, 0, 0);
      }
    }
    // (E) cos fused in-register -> z_lds (conflict-free scatter)
#pragma unroll
    for (int nt = 0; nt < 4; ++nt) {
      int col = (w * 4 + nt) * 16 + arow;
      float bp = bp_lds[col];
      float zx0 = b2f(zc[nt].x & 0xffffu), zx1 = b2f(zc[nt].x >> 16);
      float zx2 = b2f(zc[nt].y & 0xffffu), zx3 = b2f(zc[nt].y >> 16);
      z_lds[agrp * 4 + 0][col] = fcos(acc[nt][0] + bp + zx0);
      z_lds[agrp * 4 + 1][col] = fcos(acc[nt][1] + bp + zx1);
      z_lds[agrp * 4 + 2][col] = fcos(acc[nt][2] + bp + zx2);
      z_lds[agrp * 4 + 3][col] = fcos(acc[nt][3] + bp + zx3);
    }
    __syncthreads();   // barrier A
    // (G) scan: wave w scans its row's 4 gates (independent chains, ILP)
    float4 v0 = *(const float4*)&z_lds[w][0 * 256 + gcol];
    float4 v1 = *(const float4*)&z_lds[w][1 * 256 + gcol];
    float4 v2 = *(const float4*)&z_lds[w][2 * 256 + gcol];
    float4 v3 = *(const float4*)&z_lds[w][3 * 256 + gcol];
    float p0 = v0.x * v0.y * v0.z * v0.w;
    float p1 = v1.x * v1.y * v1.z * v1.w;
    float p2 = v2.x * v2.y * v2.z * v2.w;
    float p3 = v3.x * v3.y * v3.z * v3.w;
#pragma unroll
    for (int d = 1; d < 64; d <<= 1) {
      float s0 = __shfl_up(p0, (unsigned)d);
      float s1 = __shfl_up(p1, (unsigned)d);
      float s2 = __shfl_up(p2, (unsigned)d);
      float s3 = __shfl_up(p3, (unsigned)d);
      bool ok = (lane >= d);
      p0 *= ok ? s0 : 1.0f;
      p1 *= ok ? s1 : 1.0f;
      p2 *= ok ? s2 : 1.0f;
      p3 *= ok ? s3 : 1.0f;
    }
    float e0 = __shfl_up(p0, 1u), e1 = __shfl_up(p1, 1u);
    float e2 = __shfl_up(p2, 1u), e3 = __shfl_up(p3, 1u);
    if (lane == 0) { e0 = 1.f; e1 = 1.f; e2 = 1.f; e3 = 1.f; }
    float q0[4], q1[4], q2[4], q3[4];
    q0[0] = e0 * v0.x; q0[1] = q0[0] * v0.y; q0[2] = q0[1] * v0.z; q0[3] = q0[2] * v0.w;
    q1[0] = e1 * v1.x; q1[1] = q1[0] * v1.y; q1[2] = q1[1] * v1.z; q1[3] = q1[2] * v1.w;
    q2[0] = e2 * v2.x; q2[1] = q2[0] * v2.y; q2[2] = q2[1] * v2.z; q2[3] = q2[2] * v2.w;
    q3[0] = e3 * v3.x; q3[1] = q3[0] * v3.y; q3[2] = q3[1] * v3.z; q3[3] = q3[2] * v3.w;
    // (H) gates fused in-register
    u16 hb16[4];
#pragma unroll
    for (int j = 0; j < 4; ++j) {
      float fg = fsig(q0[j]);
      float ig = fsig(q1[j]);
      float ug = ftanh(q2[j]);
      float og = fsig(q3[j]);
      c[j] = fg * c[j] + ig * ug;
      float hv = og * ftanh(c[j]);
      hprev[j] = hv;
      hb16[j] = f2b(hv);
    }
    uint2 hv2;
    hv2.x = (uint32_t)hb16[0] | ((uint32_t)hb16[1] << 16);
    hv2.y = (uint32_t)hb16[2] | ((uint32_t)hb16[3] << 16);
    hq = hv2;
    *(uint2*)&h_lds[w][(lane >> 1) ^ (w & 7)][(lane & 1) * 4] = hv2;
    __syncthreads();   // barrier B
    // (J) rotate prefetch buffer
#pragma unroll
    for (int nt = 0; nt < 4; ++nt) zc[nt] = zn[nt];
  }
  // final h(Tc-1)
  {
    float4 h4; h4.x = hprev[0]; h4.y = hprev[1]; h4.z = hprev[2]; h4.w = hprev[3];
    *(float4*)(outp + ((size_t)(t0 + Tc - 1) * BATCH + r0 + w) * HID + gcol) = h4;
  }
  // persist state
  *(uint2*)(h_state + (size_t)(r0 + w) * HID + gcol) = hq;
  {
    float4 cv; cv.x = c[0]; cv.y = c[1]; cv.z = c[2]; cv.w = c[3];
    *(float4*)(c_state + (size_t)(r0 + w) * HID + gcol) = cv;
  }
  if (t0 + Tc == SEQ) {
    size_t base = (size_t)SEQ * BATCH * HID;
    float4 h4; h4.x = hprev[0]; h4.y = hprev[1]; h4.z = hprev[2]; h4.w = hprev[3];
    *(float4*)(outp + base + (size_t)(r0 + w) * HID + gcol) = h4;
    float4 cv; cv.x = c[0]; cv.y = c[1]; cv.z = c[2]; cv.w = c[3];
    *(float4*)(outp + base + (size_t)BATCH * HID + (size_t)(r0 + w) * HID + gcol) = cv;
  }
}

// ---------------------------------------------------------------------------
extern "C" void kernel_launch(void* const* d_in, const int* in_sizes, int n_in,
                              void* d_out, int out_size, void* d_ws, size_t ws_size,
                              hipStream_t stream) {
  const float* X  = (const float*)d_in[0];
  const float* Wf = (const float*)d_in[1];
  const float* bf_ = (const float*)d_in[2];
  const float* Wi = (const float*)d_in[3];
  const float* bi_ = (const float*)d_in[4];
  const float* Wu = (const float*)d_in[5];
  const float* bu_ = (const float*)d_in[6];
  const float* Wo = (const float*)d_in[7];
  const float* bo_ = (const float*)d_in[8];
  const float* pf_ = (const float*)d_in[9];
  const float* pi_ = (const float*)d_in[10];
  const float* pu_ = (const float*)d_in[11];
  const float* po_ = (const float*)d_in[12];

  char* ws = (char*)d_ws;
  u16* Whb = (u16*)ws;                                 // 512 KB
  u16* Wxb = (u16*)(ws + (512 << 10));                 // 1 MB
  u16* h_state = (u16*)(ws + (1536 << 10));            // 512 KB
  float* c_state = (float*)(ws + (2048 << 10));        // 1 MB
  u16* Zxf = (u16*)(ws + (3072 << 10));                // Tc * 2 MB (bf16 frag-major)

  size_t fixed = (size_t)3072 << 10;
  int Tc = 256;
  while (Tc > 1 && fixed + (size_t)Tc * (2u << 20) > ws_size) Tc >>= 1;
  if (fixed + (size_t)Tc * (2u << 20) > ws_size) return;

  qlstm_prep<<<3072, 256, 0, stream>>>(Wf, Wi, Wu, Wo, Wxb, Whb);
  hipMemsetAsync(h_state, 0, (512 << 10) + (1 << 20), stream);

  for (int t0 = 0; t0 < SEQ; t0 += Tc) {
    qlstm_k1<<<dim3(Tc * 64), 256, 0, stream>>>(X + (size_t)t0 * BATCH * IN_DIM, Wxb, Zxf);
    qlstm_k2<<<dim3(64), 1024, 0, stream>>>(Zxf, Whb, bf_, bi_, bu_, bo_,
                                            pf_, pi_, pu_, po_,
                                            h_state, c_state, (float*)d_out, t0, Tc);
  }
}

// Round 6
// 3527.592 us; speedup vs baseline: 1.6162x; 1.0359x over previous
//
#include <hip/hip_runtime.h>
#include <stdint.h>
#include <math.h>

#define SEQ 256
#define BATCH 1024
#define IN_DIM 512
#define HID 256
#define NCOL 1024   // 4 gates * HID

typedef float f32x4 __attribute__((ext_vector_type(4)));
typedef short bf16x8 __attribute__((ext_vector_type(8)));
typedef unsigned short u16;

__device__ __forceinline__ u16 f2b(float f) {
  union { float f; uint32_t u; } v; v.f = f;
  uint32_t r = v.u + 0x7FFFu + ((v.u >> 16) & 1u);
  return (u16)(r >> 16);
}
__device__ __forceinline__ float b2f(uint32_t h16) {
  union { uint32_t u; float f; } v; v.u = h16 << 16;
  return v.f;
}

#define LOG2E 1.4426950408889634f
__device__ __forceinline__ float fcos(float x) {
  return __builtin_amdgcn_cosf(x * 0.15915494309189535f);  // v_cos takes revolutions
}
__device__ __forceinline__ float fsig(float x) {
  return __builtin_amdgcn_rcpf(1.0f + __builtin_amdgcn_exp2f(-x * LOG2E));
}
__device__ __forceinline__ float ftanh(float x) {
  float e = __builtin_amdgcn_exp2f(x * (2.0f * LOG2E));
  return (e - 1.0f) * __builtin_amdgcn_rcpf(e + 1.0f);
}

// ---------------------------------------------------------------------------
// prep: weights -> bf16 fragment-major. Wxb: [nt(64)][kg(64)][n16][e8];
// Whb: [nt(64)][kg(32)][n16][e8]. n = gate*256 + n' (f,i,u,o).
// ---------------------------------------------------------------------------
__global__ __launch_bounds__(256) void qlstm_prep(
    const float* __restrict__ Wf, const float* __restrict__ Wi,
    const float* __restrict__ Wu, const float* __restrict__ Wo,
    u16* __restrict__ Wxb, u16* __restrict__ Whb) {
  int idx = blockIdx.x * 256 + threadIdx.x;
  if (idx >= NCOL * 768) return;
  int n = idx / 768, k = idx - n * 768;
  int g = n >> 8, nn = n & 255;
  const float* W = (g == 0) ? Wf : (g == 1) ? Wi : (g == 2) ? Wu : Wo;
  u16 b = f2b(W[nn * 768 + k]);
  int nt = n >> 4, n16 = n & 15;
  if (k < IN_DIM) {
    int kg = k >> 3, e = k & 7;
    Wxb[(((size_t)nt * 64 + kg) * 16 + n16) * 8 + e] = b;
  } else {
    int kh = k - IN_DIM, kg = kh >> 3, e = kh & 7;
    Whb[(((size_t)nt * 32 + kg) * 16 + n16) * 8 + e] = b;
  }
}

// ---------------------------------------------------------------------------
// K1: Zxf = X @ Wx.T in bf16 FRAGMENT-MAJOR: [rowblk][ntile][lane][r(4)].
// ---------------------------------------------------------------------------
__global__ __launch_bounds__(256) void qlstm_k1(
    const float* __restrict__ Xc, const u16* __restrict__ Wxb,
    u16* __restrict__ Zxf) {
  __shared__ u16 A_lds[4][128][8];   // [kg][row][e], 8KB
  int bid = blockIdx.x;
  int mt = bid >> 3, ntb = bid & 7;
  int m0 = mt * 128;
  int tid = threadIdx.x, lane = tid & 63, wave = tid >> 6;
  int wm = wave >> 1, wn = wave & 1;

  f32x4 acc[4][4];
#pragma unroll
  for (int a = 0; a < 4; ++a)
#pragma unroll
    for (int b = 0; b < 4; ++b) acc[a][b] = (f32x4){0.f, 0.f, 0.f, 0.f};

  for (int kb = 0; kb < IN_DIM; kb += 32) {
#pragma unroll
    for (int i = 0; i < 4; ++i) {
      int slot = i * 256 + tid;
      int row = slot >> 3, kseg = slot & 7;
      float4 xv = *(const float4*)(Xc + (size_t)(m0 + row) * IN_DIM + kb + kseg * 4);
      uint2 pk;
      pk.x = (uint32_t)f2b(xv.x) | ((uint32_t)f2b(xv.y) << 16);
      pk.y = (uint32_t)f2b(xv.z) | ((uint32_t)f2b(xv.w) << 16);
      *(uint2*)&A_lds[kseg >> 1][row][(kseg & 1) * 4] = pk;
    }
    __syncthreads();
    bf16x8 af[4];
#pragma unroll
    for (int fm = 0; fm < 4; ++fm) {
      int row = wm * 64 + fm * 16 + (lane & 15);
      af[fm] = *(const bf16x8*)&A_lds[lane >> 4][row][0];
    }
    int kgb = (kb >> 3) + (lane >> 4);
#pragma unroll
    for (int fn = 0; fn < 4; ++fn) {
      int ntile = ntb * 8 + wn * 4 + fn;
      bf16x8 bfr = *(const bf16x8*)(Wxb + (((size_t)ntile * 64 + kgb) * 16 + (lane & 15)) * 8);
#pragma unroll
      for (int fm = 0; fm < 4; ++fm)
        acc[fm][fn] = __builtin_amdgcn_mfma_f32_16x16x32_bf16(af[fm], bfr, acc[fm][fn], 0, 0, 0);
    }
    __syncthreads();
  }
#pragma unroll
  for (int fm = 0; fm < 4; ++fm) {
#pragma unroll
    for (int fn = 0; fn < 4; ++fn) {
      int rowblk = mt * 8 + wm * 4 + fm;
      int ntile = ntb * 8 + wn * 4 + fn;
      uint2 pk;
      pk.x = (uint32_t)f2b(acc[fm][fn][0]) | ((uint32_t)f2b(acc[fm][fn][1]) << 16);
      pk.y = (uint32_t)f2b(acc[fm][fn][2]) | ((uint32_t)f2b(acc[fm][fn][3]) << 16);
      *(uint2*)(Zxf + (((size_t)rowblk * 64 + ntile) * 64 + lane) * 4) = pk;
    }
  }
}

// ---------------------------------------------------------------------------
// K2 v4: 64 WGs x 1024 thr, __launch_bounds__(1024,4) -> 128 VGPR;
// LDS ~95KB forces 1 WG/CU. Double-buffered Whb fragment loads over kt.
// ---------------------------------------------------------------------------
__global__ __launch_bounds__(1024, 4) void qlstm_k2(
    const u16* __restrict__ Zxf, const u16* __restrict__ Whb,
    const float* __restrict__ bf_, const float* __restrict__ bi_,
    const float* __restrict__ bu_, const float* __restrict__ bo_,
    const float* __restrict__ pf_, const float* __restrict__ pi_,
    const float* __restrict__ pu_, const float* __restrict__ po_,
    u16* __restrict__ h_state, float* __restrict__ c_state,
    float* __restrict__ outp, int t0, int Tc) {
  // stride 1300: agrp bank step = 4*1300 % 32 = 16 -> 2-way (free); also
  // pushes LDS to ~95KB so only 1 WG/CU fits -> compiler gets 128 VGPRs.
  __shared__ float z_lds[16][1300];
  __shared__ u16 h_lds[16][32][8];    // [row][kg ^ (row&7)][e]
  __shared__ float bp_lds[1024];

  int tid = threadIdx.x, lane = tid & 63, w = tid >> 6;  // w: wave 0..15 == batch row
  int rg = blockIdx.x;                 // row-group 0..63
  int r0 = rg * 16;

  {
    int g = tid >> 8, nn = tid & 255;
    float bb = (g == 0 ? bf_ : g == 1 ? bi_ : g == 2 ? bu_ : bo_)[nn];
    float pp = (g == 0 ? pf_ : g == 1 ? pi_ : g == 2 ? pu_ : po_)[nn];
    bp_lds[tid] = bb + pp;
  }
  int gcol = lane * 4;                 // this thread's 4 hidden cols (row w)
  uint2 hq = *(const uint2*)(h_state + (size_t)(r0 + w) * HID + gcol);
  *(uint2*)&h_lds[w][(lane >> 1) ^ (w & 7)][(lane & 1) * 4] = hq;
  float c[4];
  {
    float4 cv = *(const float4*)(c_state + (size_t)(r0 + w) * HID + gcol);
    c[0] = cv.x; c[1] = cv.y; c[2] = cv.z; c[3] = cv.w;
  }
  float hprev[4] = {0.f, 0.f, 0.f, 0.f};
  __syncthreads();

  int arow = lane & 15, agrp = lane >> 4;
  // Whb fragment (nt, kt) = wbase + nt*4096 + kt*512 elements
  const u16* wbase = Whb + (((size_t)(w * 4) * 32 + agrp) * 16 + arow) * 8;
  // Zx fragment base for (tt, ntile=w*4+nt)
  const u16* zbase = Zxf + (((size_t)rg * 64 + (size_t)w * 4) * 64 + lane) * 4;
  const size_t ZT = (size_t)64 * 64 * 64 * 4;   // elements per timestep
  uint2 zc[4], zn[4];
#pragma unroll
  for (int nt = 0; nt < 4; ++nt)
    zc[nt] = *(const uint2*)(zbase + (size_t)nt * 256);

  for (int tt = 0; tt < Tc; ++tt) {
    // (A) prefetch Zx for tt+1
    size_t tnext = (size_t)((tt + 1 < Tc) ? tt + 1 : tt) * ZT;
#pragma unroll
    for (int nt = 0; nt < 4; ++nt)
      zn[nt] = *(const uint2*)(zbase + tnext + (size_t)nt * 256);
    // (B) store h(tt-1): drains under MFMA phase, not at a barrier
    if (tt > 0) {
      float4 h4; h4.x = hprev[0]; h4.y = hprev[1]; h4.z = hprev[2]; h4.w = hprev[3];
      *(float4*)(outp + ((size_t)(t0 + tt - 1) * BATCH + r0 + w) * HID + gcol) = h4;
    }
    // (C) A-fragments of h
    bf16x8 afr[8];
#pragma unroll
    for (int kt = 0; kt < 8; ++kt)
      afr[kt] = *(const bf16x8*)&h_lds[arow][(kt * 4 + agrp) ^ (arow & 7)][0];
    // (D) MFMA, kt-batched double-buffered B loads
    f32x4 acc[4];
    bf16x8 bcur[4], bnxt[4];
#pragma unroll
    for (int nt = 0; nt < 4; ++nt) {
      acc[nt] = (f32x4){0.f, 0.f, 0.f, 0.f};
      bcur[nt] = *(const bf16x8*)(wbase + nt * 4096);
    }
#pragma unroll
    for (int kt = 0; kt < 8; ++kt) {
      if (kt < 7) {
#pragma unroll
        for (int nt = 0; nt < 4; ++nt)
          bnxt[nt] = *(const bf16x8*)(wbase + nt * 4096 + (kt + 1) * 512);
      }
#pragma unroll
      for (int nt = 0; nt < 4; ++nt)
        acc[nt] = __builtin_amdgcn_mfma_f32_16x16x32_bf16(afr[kt], bcur[nt], acc[nt], 0, 0, 0);
      if (kt < 7) {
#pragma unroll
        for (int nt = 0; nt < 4; ++nt) bcur[nt] = bnxt[nt];
      }
    }
    // (E) cos fused in-register -> z_lds (2-way scatter, free)
#pragma unroll
    for (int nt = 0; nt < 4; ++nt) {
      int col = (w * 4 + nt) * 16 + arow;
      float bp = bp_lds[col];
      float zx0 = b2f(zc[nt].x & 0xffffu), zx1 = b2f(zc[nt].x >> 16);
      float zx2 = b2f(zc[nt].y & 0xffffu), zx3 = b2f(zc[nt].y >> 16);
      z_lds[agrp * 4 + 0][col] = fcos(acc[nt][0] + bp + zx0);
      z_lds[agrp * 4 + 1][col] = fcos(acc[nt][1] + bp + zx1);
      z_lds[agrp * 4 + 2][col] = fcos(acc[nt][2] + bp + zx2);
      z_lds[agrp * 4 + 3][col] = fcos(acc[nt][3] + bp + zx3);
    }
    __syncthreads();   // barrier A
    // (G) scan: wave w scans its row's 4 gates (independent chains, ILP)
    float4 v0 = *(const float4*)&z_lds[w][0 * 256 + gcol];
    float4 v1 = *(const float4*)&z_lds[w][1 * 256 + gcol];
    float4 v2 = *(const float4*)&z_lds[w][2 * 256 + gcol];
    float4 v3 = *(const float4*)&z_lds[w][3 * 256 + gcol];
    float p0 = v0.x * v0.y * v0.z * v0.w;
    float p1 = v1.x * v1.y * v1.z * v1.w;
    float p2 = v2.x * v2.y * v2.z * v2.w;
    float p3 = v3.x * v3.y * v3.z * v3.w;
#pragma unroll
    for (int d = 1; d < 64; d <<= 1) {
      float s0 = __shfl_up(p0, (unsigned)d);
      float s1 = __shfl_up(p1, (unsigned)d);
      float s2 = __shfl_up(p2, (unsigned)d);
      float s3 = __shfl_up(p3, (unsigned)d);
      bool ok = (lane >= d);
      p0 *= ok ? s0 : 1.0f;
      p1 *= ok ? s1 : 1.0f;
      p2 *= ok ? s2 : 1.0f;
      p3 *= ok ? s3 : 1.0f;
    }
    float e0 = __shfl_up(p0, 1u), e1 = __shfl_up(p1, 1u);
    float e2 = __shfl_up(p2, 1u), e3 = __shfl_up(p3, 1u);
    if (lane == 0) { e0 = 1.f; e1 = 1.f; e2 = 1.f; e3 = 1.f; }
    float q0[4], q1[4], q2[4], q3[4];
    q0[0] = e0 * v0.x; q0[1] = q0[0] * v0.y; q0[2] = q0[1] * v0.z; q0[3] = q0[2] * v0.w;
    q1[0] = e1 * v1.x; q1[1] = q1[0] * v1.y; q1[2] = q1[1] * v1.z; q1[3] = q1[2] * v1.w;
    q2[0] = e2 * v2.x; q2[1] = q2[0] * v2.y; q2[2] = q2[1] * v2.z; q2[3] = q2[2] * v2.w;
    q3[0] = e3 * v3.x; q3[1] = q3[0] * v3.y; q3[2] = q3[1] * v3.z; q3[3] = q3[2] * v3.w;
    // (H) gates fused in-register
    u16 hb16[4];
#pragma unroll
    for (int j = 0; j < 4; ++j) {
      float fg = fsig(q0[j]);
      float ig = fsig(q1[j]);
      float ug = ftanh(q2[j]);
      float og = fsig(q3[j]);
      c[j] = fg * c[j] + ig * ug;
      float hv = og * ftanh(c[j]);
      hprev[j] = hv;
      hb16[j] = f2b(hv);
    }
    uint2 hv2;
    hv2.x = (uint32_t)hb16[0] | ((uint32_t)hb16[1] << 16);
    hv2.y = (uint32_t)hb16[2] | ((uint32_t)hb16[3] << 16);
    hq = hv2;
    *(uint2*)&h_lds[w][(lane >> 1) ^ (w & 7)][(lane & 1) * 4] = hv2;
    __syncthreads();   // barrier B
    // (J) rotate prefetch buffer
#pragma unroll
    for (int nt = 0; nt < 4; ++nt) zc[nt] = zn[nt];
  }
  // final h(Tc-1)
  {
    float4 h4; h4.x = hprev[0]; h4.y = hprev[1]; h4.z = hprev[2]; h4.w = hprev[3];
    *(float4*)(outp + ((size_t)(t0 + Tc - 1) * BATCH + r0 + w) * HID + gcol) = h4;
  }
  // persist state
  *(uint2*)(h_state + (size_t)(r0 + w) * HID + gcol) = hq;
  {
    float4 cv; cv.x = c[0]; cv.y = c[1]; cv.z = c[2]; cv.w = c[3];
    *(float4*)(c_state + (size_t)(r0 + w) * HID + gcol) = cv;
  }
  if (t0 + Tc == SEQ) {
    size_t base = (size_t)SEQ * BATCH * HID;
    float4 h4; h4.x = hprev[0]; h4.y = hprev[1]; h4.z = hprev[2]; h4.w = hprev[3];
    *(float4*)(outp + base + (size_t)(r0 + w) * HID + gcol) = h4;
    float4 cv; cv.x = c[0]; cv.y = c[1]; cv.z = c[2]; cv.w = c[3];
    *(float4*)(outp + base + (size_t)BATCH * HID + (size_t)(r0 + w) * HID + gcol) = cv;
  }
}

// ---------------------------------------------------------------------------
extern "C" void kernel_launch(void* const* d_in, const int* in_sizes, int n_in,
                              void* d_out, int out_size, void* d_ws, size_t ws_size,
                              hipStream_t stream) {
  const float* X  = (const float*)d_in[0];
  const float* Wf = (const float*)d_in[1];
  const float* bf_ = (const float*)d_in[2];
  const float* Wi = (const float*)d_in[3];
  const float* bi_ = (const float*)d_in[4];
  const float* Wu = (const float*)d_in[5];
  const float* bu_ = (const float*)d_in[6];
  const float* Wo = (const float*)d_in[7];
  const float* bo_ = (const float*)d_in[8];
  const float* pf_ = (const float*)d_in[9];
  const float* pi_ = (const float*)d_in[10];
  const float* pu_ = (const float*)d_in[11];
  const float* po_ = (const float*)d_in[12];

  char* ws = (char*)d_ws;
  u16* Whb = (u16*)ws;                                 // 512 KB
  u16* Wxb = (u16*)(ws + (512 << 10));                 // 1 MB
  u16* h_state = (u16*)(ws + (1536 << 10));            // 512 KB
  float* c_state = (float*)(ws + (2048 << 10));        // 1 MB
  u16* Zxf = (u16*)(ws + (3072 << 10));                // Tc * 2 MB (bf16 frag-major)

  size_t fixed = (size_t)3072 << 10;
  int Tc = 256;
  while (Tc > 1 && fixed + (size_t)Tc * (2u << 20) > ws_size) Tc >>= 1;
  if (fixed + (size_t)Tc * (2u << 20) > ws_size) return;

  qlstm_prep<<<3072, 256, 0, stream>>>(Wf, Wi, Wu, Wo, Wxb, Whb);
  hipMemsetAsync(h_state, 0, (512 << 10) + (1 << 20), stream);

  for (int t0 = 0; t0 < SEQ; t0 += Tc) {
    qlstm_k1<<<dim3(Tc * 64), 256, 0, stream>>>(X + (size_t)t0 * BATCH * IN_DIM, Wxb, Zxf);
    qlstm_k2<<<dim3(64), 1024, 0, stream>>>(Zxf, Whb, bf_, bi_, bu_, bo_,
                                            pf_, pi_, pu_, po_,
                                            h_state, c_state, (float*)d_out, t0, Tc);
  }
}

// Round 7
// 3340.828 us; speedup vs baseline: 1.7066x; 1.0559x over previous
//
#include <hip/hip_runtime.h>
#include <stdint.h>
#include <math.h>

#define SEQ 256
#define BATCH 1024
#define IN_DIM 512
#define HID 256
#define NCOL 1024   // 4 gates * HID

typedef float f32x4 __attribute__((ext_vector_type(4)));
typedef short bf16x8 __attribute__((ext_vector_type(8)));
typedef unsigned short u16;

__device__ __forceinline__ u16 f2b(float f) {
  union { float f; uint32_t u; } v; v.f = f;
  uint32_t r = v.u + 0x7FFFu + ((v.u >> 16) & 1u);
  return (u16)(r >> 16);
}
__device__ __forceinline__ float b2f(uint32_t h16) {
  union { uint32_t u; float f; } v; v.u = h16 << 16;
  return v.f;
}

#define LOG2E 1.4426950408889634f
__device__ __forceinline__ float fcos(float x) {
  return __builtin_amdgcn_cosf(x * 0.15915494309189535f);  // v_cos takes revolutions
}
__device__ __forceinline__ float fsig(float x) {
  return __builtin_amdgcn_rcpf(1.0f + __builtin_amdgcn_exp2f(-x * LOG2E));
}
__device__ __forceinline__ float ftanh(float x) {
  float e = __builtin_amdgcn_exp2f(x * (2.0f * LOG2E));
  return (e - 1.0f) * __builtin_amdgcn_rcpf(e + 1.0f);
}

// Raw barrier: orders LDS (lgkmcnt) only — does NOT drain vmcnt, so global
// prefetches/stores stay in flight across it (the __syncthreads() vmcnt(0)
// drain was serializing every step on an HBM round trip).
__device__ __forceinline__ void barrier_lds_only() {
  asm volatile("s_waitcnt lgkmcnt(0)\n\ts_barrier" ::: "memory");
}

// ---------------------------------------------------------------------------
// prep: weights -> bf16 fragment-major. Wxb: [nt(64)][kg(64)][n16][e8];
// Whb: [nt(64)][kg(32)][n16][e8]. n = gate*256 + n' (f,i,u,o).
// ---------------------------------------------------------------------------
__global__ __launch_bounds__(256) void qlstm_prep(
    const float* __restrict__ Wf, const float* __restrict__ Wi,
    const float* __restrict__ Wu, const float* __restrict__ Wo,
    u16* __restrict__ Wxb, u16* __restrict__ Whb) {
  int idx = blockIdx.x * 256 + threadIdx.x;
  if (idx >= NCOL * 768) return;
  int n = idx / 768, k = idx - n * 768;
  int g = n >> 8, nn = n & 255;
  const float* W = (g == 0) ? Wf : (g == 1) ? Wi : (g == 2) ? Wu : Wo;
  u16 b = f2b(W[nn * 768 + k]);
  int nt = n >> 4, n16 = n & 15;
  if (k < IN_DIM) {
    int kg = k >> 3, e = k & 7;
    Wxb[(((size_t)nt * 64 + kg) * 16 + n16) * 8 + e] = b;
  } else {
    int kh = k - IN_DIM, kg = kh >> 3, e = kh & 7;
    Whb[(((size_t)nt * 32 + kg) * 16 + n16) * 8 + e] = b;
  }
}

// ---------------------------------------------------------------------------
// K1: Zxf = X @ Wx.T in bf16 FRAGMENT-MAJOR: [rowblk][ntile][lane][r(4)].
// ---------------------------------------------------------------------------
__global__ __launch_bounds__(256) void qlstm_k1(
    const float* __restrict__ Xc, const u16* __restrict__ Wxb,
    u16* __restrict__ Zxf) {
  __shared__ u16 A_lds[4][128][8];   // [kg][row][e], 8KB
  int bid = blockIdx.x;
  int mt = bid >> 3, ntb = bid & 7;
  int m0 = mt * 128;
  int tid = threadIdx.x, lane = tid & 63, wave = tid >> 6;
  int wm = wave >> 1, wn = wave & 1;

  f32x4 acc[4][4];
#pragma unroll
  for (int a = 0; a < 4; ++a)
#pragma unroll
    for (int b = 0; b < 4; ++b) acc[a][b] = (f32x4){0.f, 0.f, 0.f, 0.f};

  for (int kb = 0; kb < IN_DIM; kb += 32) {
#pragma unroll
    for (int i = 0; i < 4; ++i) {
      int slot = i * 256 + tid;
      int row = slot >> 3, kseg = slot & 7;
      float4 xv = *(const float4*)(Xc + (size_t)(m0 + row) * IN_DIM + kb + kseg * 4);
      uint2 pk;
      pk.x = (uint32_t)f2b(xv.x) | ((uint32_t)f2b(xv.y) << 16);
      pk.y = (uint32_t)f2b(xv.z) | ((uint32_t)f2b(xv.w) << 16);
      *(uint2*)&A_lds[kseg >> 1][row][(kseg & 1) * 4] = pk;
    }
    __syncthreads();
    bf16x8 af[4];
#pragma unroll
    for (int fm = 0; fm < 4; ++fm) {
      int row = wm * 64 + fm * 16 + (lane & 15);
      af[fm] = *(const bf16x8*)&A_lds[lane >> 4][row][0];
    }
    int kgb = (kb >> 3) + (lane >> 4);
#pragma unroll
    for (int fn = 0; fn < 4; ++fn) {
      int ntile = ntb * 8 + wn * 4 + fn;
      bf16x8 bfr = *(const bf16x8*)(Wxb + (((size_t)ntile * 64 + kgb) * 16 + (lane & 15)) * 8);
#pragma unroll
      for (int fm = 0; fm < 4; ++fm)
        acc[fm][fn] = __builtin_amdgcn_mfma_f32_16x16x32_bf16(af[fm], bfr, acc[fm][fn], 0, 0, 0);
    }
    __syncthreads();
  }
#pragma unroll
  for (int fm = 0; fm < 4; ++fm) {
#pragma unroll
    for (int fn = 0; fn < 4; ++fn) {
      int rowblk = mt * 8 + wm * 4 + fm;
      int ntile = ntb * 8 + wn * 4 + fn;
      uint2 pk;
      pk.x = (uint32_t)f2b(acc[fm][fn][0]) | ((uint32_t)f2b(acc[fm][fn][1]) << 16);
      pk.y = (uint32_t)f2b(acc[fm][fn][2]) | ((uint32_t)f2b(acc[fm][fn][3]) << 16);
      *(uint2*)(Zxf + (((size_t)rowblk * 64 + ntile) * 64 + lane) * 4) = pk;
    }
  }
}

// ---------------------------------------------------------------------------
// K2 v5: identical structure to v4 except the two in-loop barriers are raw
// lgkm-only barriers (no vmcnt drain) -> Zx prefetch + h store stay in
// flight across steps. sched_barrier pins the prefetch at loop top.
// ---------------------------------------------------------------------------
__global__ __launch_bounds__(1024, 4) void qlstm_k2(
    const u16* __restrict__ Zxf, const u16* __restrict__ Whb,
    const float* __restrict__ bf_, const float* __restrict__ bi_,
    const float* __restrict__ bu_, const float* __restrict__ bo_,
    const float* __restrict__ pf_, const float* __restrict__ pi_,
    const float* __restrict__ pu_, const float* __restrict__ po_,
    u16* __restrict__ h_state, float* __restrict__ c_state,
    float* __restrict__ outp, int t0, int Tc) {
  // stride 1300: agrp bank step = 4*1300 % 32 = 16 -> 2-way (free); also
  // pushes LDS to ~95KB so only 1 WG/CU fits.
  __shared__ float z_lds[16][1300];
  __shared__ u16 h_lds[16][32][8];    // [row][kg ^ (row&7)][e]
  __shared__ float bp_lds[1024];

  int tid = threadIdx.x, lane = tid & 63, w = tid >> 6;  // w: wave 0..15 == batch row
  int rg = blockIdx.x;                 // row-group 0..63
  int r0 = rg * 16;

  {
    int g = tid >> 8, nn = tid & 255;
    float bb = (g == 0 ? bf_ : g == 1 ? bi_ : g == 2 ? bu_ : bo_)[nn];
    float pp = (g == 0 ? pf_ : g == 1 ? pi_ : g == 2 ? pu_ : po_)[nn];
    bp_lds[tid] = bb + pp;
  }
  int gcol = lane * 4;                 // this thread's 4 hidden cols (row w)
  uint2 hq = *(const uint2*)(h_state + (size_t)(r0 + w) * HID + gcol);
  *(uint2*)&h_lds[w][(lane >> 1) ^ (w & 7)][(lane & 1) * 4] = hq;
  float c[4];
  {
    float4 cv = *(const float4*)(c_state + (size_t)(r0 + w) * HID + gcol);
    c[0] = cv.x; c[1] = cv.y; c[2] = cv.z; c[3] = cv.w;
  }
  float hprev[4] = {0.f, 0.f, 0.f, 0.f};
  __syncthreads();

  int arow = lane & 15, agrp = lane >> 4;
  // Whb fragment (nt, kt) = wbase + nt*4096 + kt*512 elements
  const u16* wbase = Whb + (((size_t)(w * 4) * 32 + agrp) * 16 + arow) * 8;
  // Zx fragment base for (tt, ntile=w*4+nt)
  const u16* zbase = Zxf + (((size_t)rg * 64 + (size_t)w * 4) * 64 + lane) * 4;
  const size_t ZT = (size_t)64 * 64 * 64 * 4;   // elements per timestep
  uint2 zc[4], zn[4];
#pragma unroll
  for (int nt = 0; nt < 4; ++nt)
    zc[nt] = *(const uint2*)(zbase + (size_t)nt * 256);

  for (int tt = 0; tt < Tc; ++tt) {
    // (A) prefetch Zx for tt+1 — pinned here; survives barriers below
    size_t tnext = (size_t)((tt + 1 < Tc) ? tt + 1 : tt) * ZT;
#pragma unroll
    for (int nt = 0; nt < 4; ++nt)
      zn[nt] = *(const uint2*)(zbase + tnext + (size_t)nt * 256);
    __builtin_amdgcn_sched_barrier(0);
    // (B) store h(tt-1): drains lazily (no vmcnt(0) at barriers anymore)
    if (tt > 0) {
      float4 h4; h4.x = hprev[0]; h4.y = hprev[1]; h4.z = hprev[2]; h4.w = hprev[3];
      *(float4*)(outp + ((size_t)(t0 + tt - 1) * BATCH + r0 + w) * HID + gcol) = h4;
    }
    // (C) A-fragments of h
    bf16x8 afr[8];
#pragma unroll
    for (int kt = 0; kt < 8; ++kt)
      afr[kt] = *(const bf16x8*)&h_lds[arow][(kt * 4 + agrp) ^ (arow & 7)][0];
    // (D) MFMA, kt-batched double-buffered B loads
    f32x4 acc[4];
    bf16x8 bcur[4], bnxt[4];
#pragma unroll
    for (int nt = 0; nt < 4; ++nt) {
      acc[nt] = (f32x4){0.f, 0.f, 0.f, 0.f};
      bcur[nt] = *(const bf16x8*)(wbase + nt * 4096);
    }
#pragma unroll
    for (int kt = 0; kt < 8; ++kt) {
      if (kt < 7) {
#pragma unroll
        for (int nt = 0; nt < 4; ++nt)
          bnxt[nt] = *(const bf16x8*)(wbase + nt * 4096 + (kt + 1) * 512);
      }
#pragma unroll
      for (int nt = 0; nt < 4; ++nt)
        acc[nt] = __builtin_amdgcn_mfma_f32_16x16x32_bf16(afr[kt], bcur[nt], acc[nt], 0, 0, 0);
      if (kt < 7) {
#pragma unroll
        for (int nt = 0; nt < 4; ++nt) bcur[nt] = bnxt[nt];
      }
    }
    // (E) cos fused in-register -> z_lds (2-way scatter, free)
#pragma unroll
    for (int nt = 0; nt < 4; ++nt) {
      int col = (w * 4 + nt) * 16 + arow;
      float bp = bp_lds[col];
      float zx0 = b2f(zc[nt].x & 0xffffu), zx1 = b2f(zc[nt].x >> 16);
      float zx2 = b2f(zc[nt].y & 0xffffu), zx3 = b2f(zc[nt].y >> 16);
      z_lds[agrp * 4 + 0][col] = fcos(acc[nt][0] + bp + zx0);
      z_lds[agrp * 4 + 1][col] = fcos(acc[nt][1] + bp + zx1);
      z_lds[agrp * 4 + 2][col] = fcos(acc[nt][2] + bp + zx2);
      z_lds[agrp * 4 + 3][col] = fcos(acc[nt][3] + bp + zx3);
    }
    barrier_lds_only();   // barrier A (no vmcnt drain)
    // (G) scan: wave w scans its row's 4 gates (independent chains, ILP)
    float4 v0 = *(const float4*)&z_lds[w][0 * 256 + gcol];
    float4 v1 = *(const float4*)&z_lds[w][1 * 256 + gcol];
    float4 v2 = *(const float4*)&z_lds[w][2 * 256 + gcol];
    float4 v3 = *(const float4*)&z_lds[w][3 * 256 + gcol];
    float p0 = v0.x * v0.y * v0.z * v0.w;
    float p1 = v1.x * v1.y * v1.z * v1.w;
    float p2 = v2.x * v2.y * v2.z * v2.w;
    float p3 = v3.x * v3.y * v3.z * v3.w;
#pragma unroll
    for (int d = 1; d < 64; d <<= 1) {
      float s0 = __shfl_up(p0, (unsigned)d);
      float s1 = __shfl_up(p1, (unsigned)d);
      float s2 = __shfl_up(p2, (unsigned)d);
      float s3 = __shfl_up(p3, (unsigned)d);
      bool ok = (lane >= d);
      p0 *= ok ? s0 : 1.0f;
      p1 *= ok ? s1 : 1.0f;
      p2 *= ok ? s2 : 1.0f;
      p3 *= ok ? s3 : 1.0f;
    }
    float e0 = __shfl_up(p0, 1u), e1 = __shfl_up(p1, 1u);
    float e2 = __shfl_up(p2, 1u), e3 = __shfl_up(p3, 1u);
    if (lane == 0) { e0 = 1.f; e1 = 1.f; e2 = 1.f; e3 = 1.f; }
    float q0[4], q1[4], q2[4], q3[4];
    q0[0] = e0 * v0.x; q0[1] = q0[0] * v0.y; q0[2] = q0[1] * v0.z; q0[3] = q0[2] * v0.w;
    q1[0] = e1 * v1.x; q1[1] = q1[0] * v1.y; q1[2] = q1[1] * v1.z; q1[3] = q1[2] * v1.w;
    q2[0] = e2 * v2.x; q2[1] = q2[0] * v2.y; q2[2] = q2[1] * v2.z; q2[3] = q2[2] * v2.w;
    q3[0] = e3 * v3.x; q3[1] = q3[0] * v3.y; q3[2] = q3[1] * v3.z; q3[3] = q3[2] * v3.w;
    // (H) gates fused in-register
    u16 hb16[4];
#pragma unroll
    for (int j = 0; j < 4; ++j) {
      float fg = fsig(q0[j]);
      float ig = fsig(q1[j]);
      float ug = ftanh(q2[j]);
      float og = fsig(q3[j]);
      c[j] = fg * c[j] + ig * ug;
      float hv = og * ftanh(c[j]);
      hprev[j] = hv;
      hb16[j] = f2b(hv);
    }
    uint2 hv2;
    hv2.x = (uint32_t)hb16[0] | ((uint32_t)hb16[1] << 16);
    hv2.y = (uint32_t)hb16[2] | ((uint32_t)hb16[3] << 16);
    hq = hv2;
    *(uint2*)&h_lds[w][(lane >> 1) ^ (w & 7)][(lane & 1) * 4] = hv2;
    barrier_lds_only();   // barrier B (no vmcnt drain)
    // (J) rotate prefetch buffer
#pragma unroll
    for (int nt = 0; nt < 4; ++nt) zc[nt] = zn[nt];
  }
  // final h(Tc-1)
  {
    float4 h4; h4.x = hprev[0]; h4.y = hprev[1]; h4.z = hprev[2]; h4.w = hprev[3];
    *(float4*)(outp + ((size_t)(t0 + Tc - 1) * BATCH + r0 + w) * HID + gcol) = h4;
  }
  // persist state
  *(uint2*)(h_state + (size_t)(r0 + w) * HID + gcol) = hq;
  {
    float4 cv; cv.x = c[0]; cv.y = c[1]; cv.z = c[2]; cv.w = c[3];
    *(float4*)(c_state + (size_t)(r0 + w) * HID + gcol) = cv;
  }
  if (t0 + Tc == SEQ) {
    size_t base = (size_t)SEQ * BATCH * HID;
    float4 h4; h4.x = hprev[0]; h4.y = hprev[1]; h4.z = hprev[2]; h4.w = hprev[3];
    *(float4*)(outp + base + (size_t)(r0 + w) * HID + gcol) = h4;
    float4 cv; cv.x = c[0]; cv.y = c[1]; cv.z = c[2]; cv.w = c[3];
    *(float4*)(outp + base + (size_t)BATCH * HID + (size_t)(r0 + w) * HID + gcol) = cv;
  }
}

// ---------------------------------------------------------------------------
extern "C" void kernel_launch(void* const* d_in, const int* in_sizes, int n_in,
                              void* d_out, int out_size, void* d_ws, size_t ws_size,
                              hipStream_t stream) {
  const float* X  = (const float*)d_in[0];
  const float* Wf = (const float*)d_in[1];
  const float* bf_ = (const float*)d_in[2];
  const float* Wi = (const float*)d_in[3];
  const float* bi_ = (const float*)d_in[4];
  const float* Wu = (const float*)d_in[5];
  const float* bu_ = (const float*)d_in[6];
  const float* Wo = (const float*)d_in[7];
  const float* bo_ = (const float*)d_in[8];
  const float* pf_ = (const float*)d_in[9];
  const float* pi_ = (const float*)d_in[10];
  const float* pu_ = (const float*)d_in[11];
  const float* po_ = (const float*)d_in[12];

  char* ws = (char*)d_ws;
  u16* Whb = (u16*)ws;                                 // 512 KB
  u16* Wxb = (u16*)(ws + (512 << 10));                 // 1 MB
  u16* h_state = (u16*)(ws + (1536 << 10));            // 512 KB
  float* c_state = (float*)(ws + (2048 << 10));        // 1 MB
  u16* Zxf = (u16*)(ws + (3072 << 10));                // Tc * 2 MB (bf16 frag-major)

  size_t fixed = (size_t)3072 << 10;
  int Tc = 256;
  while (Tc > 1 && fixed + (size_t)Tc * (2u << 20) > ws_size) Tc >>= 1;
  if (fixed + (size_t)Tc * (2u << 20) > ws_size) return;

  qlstm_prep<<<3072, 256, 0, stream>>>(Wf, Wi, Wu, Wo, Wxb, Whb);
  hipMemsetAsync(h_state, 0, (512 << 10) + (1 << 20), stream);

  for (int t0 = 0; t0 < SEQ; t0 += Tc) {
    qlstm_k1<<<dim3(Tc * 64), 256, 0, stream>>>(X + (size_t)t0 * BATCH * IN_DIM, Wxb, Zxf);
    qlstm_k2<<<dim3(64), 1024, 0, stream>>>(Zxf, Whb, bf_, bi_, bu_, bo_,
                                            pf_, pi_, pu_, po_,
                                            h_state, c_state, (float*)d_out, t0, Tc);
  }
}